// Round 1
// baseline (534.282 us; speedup 1.0000x reference)
//
#include <hip/hip_runtime.h>
#include <hip/hip_bf16.h>

using short8 = __attribute__((ext_vector_type(8))) short;
using short4v = __attribute__((ext_vector_type(4))) short;
using f32x4 = __attribute__((ext_vector_type(4))) float;

#define MFMA(a, b, c) __builtin_amdgcn_mfma_f32_16x16x32_bf16((a), (b), (c), 0, 0, 0)

// LDS geometry (element strides chosen for <=2-way bank conflicts on ds_read_b128)
#define XP 264       // xb / ob row stride (bf16 elems), 64 rows
#define QKP 40       // q/k row stride, 64 rows
#define VTP 72       // vt row stride, 32 rows
#define PP 72        // p row stride, 64 rows (overlays q+k region)
#define HSTRIDE 7424 // per-head elems: q 64*40=2560, k 2560, vt 32*72=2304

__global__ void prep_weights(const float* __restrict__ qkv_w, const float* __restrict__ proj_w,
                             __hip_bfloat16* __restrict__ wq_t, __hip_bfloat16* __restrict__ wp_t) {
    int j = blockIdx.x, t = threadIdx.x;
    if (j < 768) {
        wq_t[j * 256 + t] = __float2bfloat16(qkv_w[t * 768 + j]);
    } else {
        int j2 = j - 768;
        wp_t[j2 * 256 + t] = __float2bfloat16(proj_w[t * 256 + j2]);
    }
}

__global__ __launch_bounds__(512, 2) void swin_fused(
    const float* __restrict__ x, const float* __restrict__ mask,
    const float* __restrict__ qkv_b, const float* __restrict__ proj_b,
    const float* __restrict__ rpb,
    const __hip_bfloat16* __restrict__ wq_t, const __hip_bfloat16* __restrict__ wp_t,
    float* __restrict__ out)
{
    __shared__ __align__(16) __hip_bfloat16 xb[64 * XP];       // 33792 B; reused as O-buffer
    __shared__ __align__(16) __hip_bfloat16 hbuf[8 * HSTRIDE]; // 118784 B

    const int tid = threadIdx.x;
    const int h = tid >> 6;      // wave id = head
    const int lane = tid & 63;
    const int lg = lane >> 4;    // 0..3
    const int li = lane & 15;    // 0..15
    const int b = blockIdx.x;
    const int w = b & 63;        // window index for mask

    // ---- phase 1: x -> LDS (bf16) ----
    {
        const float* xp = x + (size_t)b * 16384;
#pragma unroll
        for (int it = 0; it < 8; ++it) {
            int e = (it * 512 + tid) * 4;
            int row = e >> 8, col = e & 255;
            float4 v = *(const float4*)(xp + e);
            __hip_bfloat16 tmp[4] = {__float2bfloat16(v.x), __float2bfloat16(v.y),
                                     __float2bfloat16(v.z), __float2bfloat16(v.w)};
            *(short4v*)(&xb[row * XP + col]) = *(const short4v*)tmp;
        }
    }
    __syncthreads();

    // ---- phase 2: QKV for head h (wave-private LDS output) ----
    __hip_bfloat16* qh = &hbuf[h * HSTRIDE];
    __hip_bfloat16* kh = qh + 2560;
    __hip_bfloat16* vth = qh + 5120;
    {
        f32x4 acc[4][6];
#pragma unroll
        for (int i = 0; i < 4; ++i)
#pragma unroll
            for (int j = 0; j < 6; ++j) acc[i][j] = (f32x4)0.f;
#pragma unroll
        for (int kt = 0; kt < 8; ++kt) {
            short8 a[4], bb[6];
#pragma unroll
            for (int mt = 0; mt < 4; ++mt)
                a[mt] = *(const short8*)(&xb[(mt * 16 + li) * XP + kt * 32 + lg * 8]);
#pragma unroll
            for (int nt = 0; nt < 6; ++nt) {
                int sel = nt >> 1, c16 = nt & 1;
                int wcol = sel * 256 + h * 32 + c16 * 16 + li;
                bb[nt] = *(const short8*)(wq_t + wcol * 256 + kt * 32 + lg * 8);
            }
#pragma unroll
            for (int mt = 0; mt < 4; ++mt)
#pragma unroll
                for (int nt = 0; nt < 6; ++nt)
                    acc[mt][nt] = MFMA(a[mt], bb[nt], acc[mt][nt]);
        }
        const float scale = 0.17677669529663687f; // 32^-0.5, folded into q
#pragma unroll
        for (int nt = 0; nt < 6; ++nt) {
            int sel = nt >> 1, c16 = nt & 1;
            int dim = c16 * 16 + li;
            float bias = qkv_b[sel * 256 + h * 32 + dim];
#pragma unroll
            for (int mt = 0; mt < 4; ++mt)
#pragma unroll
                for (int r = 0; r < 4; ++r) {
                    int tok = mt * 16 + lg * 4 + r;
                    float v = acc[mt][nt][r] + bias;
                    if (sel == 0)      qh[tok * QKP + dim] = __float2bfloat16(v * scale);
                    else if (sel == 1) kh[tok * QKP + dim] = __float2bfloat16(v);
                    else               vth[dim * VTP + tok] = __float2bfloat16(v);
                }
        }
    }
    __syncthreads(); // all xb reads done; xb may be reused as O-buffer

    // ---- phase 3/4: attention for head h ----
    f32x4 o[4][2];
    float rinv[4][4];
    {
        short8 aq[4], bk[4];
#pragma unroll
        for (int mt = 0; mt < 4; ++mt) aq[mt] = *(const short8*)(&qh[(mt * 16 + li) * QKP + lg * 8]);
#pragma unroll
        for (int nt = 0; nt < 4; ++nt) bk[nt] = *(const short8*)(&kh[(nt * 16 + li) * QKP + lg * 8]);
        f32x4 s[4][4];
#pragma unroll
        for (int mt = 0; mt < 4; ++mt)
#pragma unroll
            for (int nt = 0; nt < 4; ++nt) s[mt][nt] = MFMA(aq[mt], bk[nt], (f32x4)0.f);

        // rel-pos bias (inline index) + window mask (fp32 from L2)
        const float* mw = mask + w * 4096;
#pragma unroll
        for (int mt = 0; mt < 4; ++mt)
#pragma unroll
            for (int r = 0; r < 4; ++r) {
                int m = mt * 16 + lg * 4 + r;
                int ri = m >> 3, ci = m & 7;
#pragma unroll
                for (int nt = 0; nt < 4; ++nt) {
                    int n = nt * 16 + li;
                    int rj = n >> 3, cj = n & 7;
                    int idx = (ri - rj + 7) * 15 + (ci - cj + 7);
                    s[mt][nt][r] += rpb[idx * 8 + h] + mw[m * 64 + n];
                }
            }
        // softmax over n (across 4 in-lane tiles x 16 lanes), deferred normalization
#pragma unroll
        for (int mt = 0; mt < 4; ++mt)
#pragma unroll
            for (int r = 0; r < 4; ++r) {
                float mx = fmaxf(fmaxf(s[mt][0][r], s[mt][1][r]), fmaxf(s[mt][2][r], s[mt][3][r]));
#pragma unroll
                for (int off = 1; off < 16; off <<= 1) mx = fmaxf(mx, __shfl_xor(mx, off));
                float sum = 0.f;
#pragma unroll
                for (int nt = 0; nt < 4; ++nt) {
                    float p = __expf(s[mt][nt][r] - mx);
                    s[mt][nt][r] = p;
                    sum += p;
                }
#pragma unroll
                for (int off = 1; off < 16; off <<= 1) sum += __shfl_xor(sum, off);
                rinv[mt][r] = 1.f / sum;
            }
        // P -> LDS (overlay on dead q+k region; wave-private, no barrier needed)
        __hip_bfloat16* ph = qh;
#pragma unroll
        for (int mt = 0; mt < 4; ++mt)
#pragma unroll
            for (int r = 0; r < 4; ++r) {
                int m = mt * 16 + lg * 4 + r;
#pragma unroll
                for (int nt = 0; nt < 4; ++nt)
                    ph[m * PP + nt * 16 + li] = __float2bfloat16(s[mt][nt][r]);
            }
        // PV
#pragma unroll
        for (int mt = 0; mt < 4; ++mt)
#pragma unroll
            for (int nt = 0; nt < 2; ++nt) o[mt][nt] = (f32x4)0.f;
#pragma unroll
        for (int kt = 0; kt < 2; ++kt) {
            short8 pa[4], vb[2];
#pragma unroll
            for (int mt = 0; mt < 4; ++mt)
                pa[mt] = *(const short8*)(&ph[(mt * 16 + li) * PP + kt * 32 + lg * 8]);
#pragma unroll
            for (int nt = 0; nt < 2; ++nt)
                vb[nt] = *(const short8*)(&vth[(nt * 16 + li) * VTP + kt * 32 + lg * 8]);
#pragma unroll
            for (int mt = 0; mt < 4; ++mt)
#pragma unroll
                for (int nt = 0; nt < 2; ++nt) o[mt][nt] = MFMA(pa[mt], vb[nt], o[mt][nt]);
        }
    }
    // O (normalized) -> ob (= xb region), cols h*32..h*32+31
#pragma unroll
    for (int mt = 0; mt < 4; ++mt)
#pragma unroll
        for (int nt = 0; nt < 2; ++nt)
#pragma unroll
            for (int r = 0; r < 4; ++r) {
                int m = mt * 16 + lg * 4 + r;
                xb[m * XP + h * 32 + nt * 16 + li] = __float2bfloat16(o[mt][nt][r] * rinv[mt][r]);
            }
    __syncthreads();

    // ---- phase 5: proj; wave h -> out cols h*32..h*32+31 ----
    {
        f32x4 po[4][2];
#pragma unroll
        for (int mt = 0; mt < 4; ++mt)
#pragma unroll
            for (int nt = 0; nt < 2; ++nt) po[mt][nt] = (f32x4)0.f;
#pragma unroll
        for (int kt = 0; kt < 8; ++kt) {
            short8 a[4], bb[2];
#pragma unroll
            for (int mt = 0; mt < 4; ++mt)
                a[mt] = *(const short8*)(&xb[(mt * 16 + li) * XP + kt * 32 + lg * 8]);
#pragma unroll
            for (int nt = 0; nt < 2; ++nt) {
                int col = h * 32 + nt * 16 + li;
                bb[nt] = *(const short8*)(wp_t + col * 256 + kt * 32 + lg * 8);
            }
#pragma unroll
            for (int mt = 0; mt < 4; ++mt)
#pragma unroll
                for (int nt = 0; nt < 2; ++nt) po[mt][nt] = MFMA(a[mt], bb[nt], po[mt][nt]);
        }
        float* op = out + (size_t)b * 16384;
#pragma unroll
        for (int nt = 0; nt < 2; ++nt) {
            int col = h * 32 + nt * 16 + li;
            float pb = proj_b[col];
#pragma unroll
            for (int mt = 0; mt < 4; ++mt)
#pragma unroll
                for (int r = 0; r < 4; ++r) {
                    int m = mt * 16 + lg * 4 + r;
                    op[m * 256 + col] = po[mt][nt][r] + pb;
                }
        }
    }
}

extern "C" void kernel_launch(void* const* d_in, const int* in_sizes, int n_in,
                              void* d_out, int out_size, void* d_ws, size_t ws_size,
                              hipStream_t stream) {
    const float* x      = (const float*)d_in[0];
    const float* mask   = (const float*)d_in[1];
    const float* qkv_w  = (const float*)d_in[2];
    const float* qkv_b  = (const float*)d_in[3];
    const float* proj_w = (const float*)d_in[4];
    const float* proj_b = (const float*)d_in[5];
    const float* rpb    = (const float*)d_in[6];

    __hip_bfloat16* wq_t = (__hip_bfloat16*)d_ws;          // [768][256] bf16
    __hip_bfloat16* wp_t = wq_t + 768 * 256;               // [256][256] bf16

    prep_weights<<<1024, 256, 0, stream>>>(qkv_w, proj_w, wq_t, wp_t);
    swin_fused<<<4096, 512, 0, stream>>>(x, mask, qkv_b, proj_b, rpb, wq_t, wp_t, (float*)d_out);
}